// Round 1
// baseline (214.864 us; speedup 1.0000x reference)
//
#include <hip/hip_runtime.h>

// LSTM (B=8192, T=512, H=5) + MLP 5->32->32->5, fp32.
// Round 10: free the register allocator + swizzle broadcast.
//  - R9 diagnosis: launch_bounds(64,1) only sets MIN waves/EU; the
//    allocator still targeted high occupancy, capped arch VGPRs at ~72,
//    and shuffled ~85 insts/step through AGPRs (v_accvgpr_*). Grid is
//    exactly 1 wave/SIMD (1024 waves / 1024 SIMDs), so extra occupancy
//    headroom is unreachable. amdgpu_waves_per_eu(1,1) unlocks the full
//    512-reg budget -> AGPR churn should vanish (watch VGPR_Count).
//  - h broadcast: 9-op depth-2 DPP sequence -> 5 independent
//    ds_swizzle_b32 (BitMode src = (lane&0x18)|k). Flat chain, off the
//    VALU pipe; latency hides under next step's 20 h-independent x-FMAs.
//  - Same trick broadcasts xlast in the epilogue; sh[][] LDS dropped.
//  - x staged through LDS (R8-proven): 32-step double-buffered chunks,
//    RSTR=164 -> 8 groups' ds_read_b128 hit disjoint bank quads.
//  - Activation scales pre-folded (R7-proven). Math bit-identical.

#define LOG2E 1.44269504088896f

__device__ __forceinline__ float hexp2(float x) { return __builtin_amdgcn_exp2f(x); }
__device__ __forceinline__ float hrcp(float x)  { return __builtin_amdgcn_rcpf(x); }

// ds_swizzle broadcast: src lane = (lane & 0x18) | K  (BitMode, xor=0)
template<int PAT>
__device__ __forceinline__ float swz(float x) {
  int r = __builtin_amdgcn_ds_swizzle(__builtin_bit_cast(int, x), PAT);
  return __builtin_bit_cast(float, r);
}
#define SWZ_BCAST(K) (0x18 | ((K) << 5))

constexpr int TT   = 512;
constexpr int HD   = 5;
constexpr int RPB  = 8;     // rows per wave (8 lanes each)
constexpr int CHNK = 32;    // steps per LDS chunk
constexpr int RSTR = 164;   // padded LDS row stride: group g at bank 4g
constexpr int XOFF = RPB * RSTR;
constexpr int NCH  = TT / CHNK;

__global__ __attribute__((amdgpu_flat_work_group_size(64, 64),
                          amdgpu_waves_per_eu(1, 1)))
void lstm_mlp_kernel(
    const float* __restrict__ x,   const float* __restrict__ Wih,
    const float* __restrict__ Whh, const float* __restrict__ bih,
    const float* __restrict__ bhh, const float* __restrict__ W1,
    const float* __restrict__ b1,  const float* __restrict__ W2,
    const float* __restrict__ b2,  const float* __restrict__ W3,
    const float* __restrict__ b3,  float* __restrict__ out, int B)
{
  const int lane = threadIdx.x;
  const int grp  = lane >> 3;           // row within block (0..7)
  const int j    = lane & 7;            // unit owned (valid if j<5)
  const int jj   = (j < 5) ? j : 0;
  const int blockRow = blockIdx.x * RPB;
  const int row  = blockRow + grp;
  const bool act = (j < 5) && (row < B);

  __shared__ float xbuf[2 * XOFF];
  __shared__ float s1[RPB][32];
  __shared__ float s2[RPB][32];

  // ---- per-lane weights (rows {j,5+j,10+j,15+j}), activation pre-scaled --
  float wih[4][5], whh[4][5], bsum[4];
#pragma unroll
  for (int G = 0; G < 4; ++G) {
    const float sc = (G == 2) ? (2.0f * LOG2E) : (-LOG2E);
#pragma unroll
    for (int k = 0; k < 5; ++k) {
      wih[G][k] = Wih[(G * 5 + jj) * 5 + k] * sc;
      whh[G][k] = Whh[(G * 5 + jj) * 5 + k] * sc;
    }
    bsum[G] = (bih[G * 5 + jj] + bhh[G * 5 + jj]) * sc;
  }

  const int rowc = (row < B) ? row : (B - 1);
  const float xlast = x[(size_t)rowc * (TT * HD) + 511 * HD + jj];

  // ---- staging: 5x16B per lane per 32-step chunk ----
  const float4* gp[5];
  int wa[5];
#pragma unroll
  for (int i = 0; i < 5; ++i) {
    int u  = i * 64 + lane;
    int r  = u / 40;
    int o4 = u - r * 40;
    int gr = blockRow + r; if (gr >= B) gr = B - 1;
    gp[i]  = (const float4*)(x + (size_t)gr * (TT * HD)) + o4;
    wa[i]  = r * RSTR + o4 * 4;
  }

  float4 st0, st1, st2, st3, st4;
  st0 = *gp[0]; gp[0] += 40; st1 = *gp[1]; gp[1] += 40;
  st2 = *gp[2]; gp[2] += 40; st3 = *gp[3]; gp[3] += 40;
  st4 = *gp[4]; gp[4] += 40;
  *(float4*)&xbuf[wa[0]] = st0; *(float4*)&xbuf[wa[1]] = st1;
  *(float4*)&xbuf[wa[2]] = st2; *(float4*)&xbuf[wa[3]] = st3;
  *(float4*)&xbuf[wa[4]] = st4;
  st0 = *gp[0]; gp[0] += 40; st1 = *gp[1]; gp[1] += 40;
  st2 = *gp[2]; gp[2] += 40; st3 = *gp[3]; gp[3] += 40;
  st4 = *gp[4]; gp[4] += 40;

  // ---- recurrence state ----
  float c = 0.0f;
  float hv0 = 0.f, hv1 = 0.f, hv2 = 0.f, hv3 = 0.f, hv4 = 0.f;

  auto step = [&](float x0, float x1, float x2, float x3, float x4) {
    float z[4];
#pragma unroll
    for (int G = 0; G < 4; ++G) {
      float a = bsum[G];                 // x-part: independent of h
      a = fmaf(x0, wih[G][0], a);
      a = fmaf(x1, wih[G][1], a);
      a = fmaf(x2, wih[G][2], a);
      a = fmaf(x3, wih[G][3], a);
      a = fmaf(x4, wih[G][4], a);
      a = fmaf(hv0, whh[G][0], a);       // h-part: 5 FMA from hv-ready
      a = fmaf(hv1, whh[G][1], a);
      a = fmaf(hv2, whh[G][2], a);
      a = fmaf(hv3, whh[G][3], a);
      a = fmaf(hv4, whh[G][4], a);
      z[G] = a;
    }
    float ig = hrcp(1.0f + hexp2(z[0]));
    float fg = hrcp(1.0f + hexp2(z[1]));
    float gv = fmaf(-2.0f, hrcp(1.0f + hexp2(z[2])), 1.0f);
    float og = hrcp(1.0f + hexp2(z[3]));
    c = fmaf(fg, c, ig * gv);
    float th = fmaf(-2.0f, hrcp(1.0f + hexp2(c * (2.0f * LOG2E))), 1.0f);
    float h  = og * th;
    // ---- 5-value broadcast to the 8-lane group: 5 flat ds_swizzles ----
    // lane j=0..4 of each group holds h_j; src lane = (lane & 0x18) | k.
    hv0 = swz<SWZ_BCAST(0)>(h);
    hv1 = swz<SWZ_BCAST(1)>(h);
    hv2 = swz<SWZ_BCAST(2)>(h);
    hv3 = swz<SWZ_BCAST(3)>(h);
    hv4 = swz<SWZ_BCAST(4)>(h);
  };

  auto step4 = [&](float4 A, float4 Bv, float4 C, float4 D, float4 E) {
    step(A.x, A.y, A.z, A.w, Bv.x);
    step(Bv.y, Bv.z, Bv.w, C.x, C.y);
    step(C.z, C.w, D.x, D.y, D.z);
    step(D.w, E.x, E.y, E.z, E.w);
  };

  auto rdg = [&](int fi, float4& A, float4& Bv, float4& C, float4& D, float4& E) {
    const float4* p = (const float4*)&xbuf[fi];
    A = p[0]; Bv = p[1]; C = p[2]; D = p[3]; E = p[4];
  };

  float4 A0, A1, A2, A3, A4;
  float4 B0, B1, B2, B3, B4;

#pragma unroll 1
  for (int ch = 0; ch < NCH; ++ch) {
    const int bo_cur  = (ch & 1) ? XOFF : 0;
    const int bo_next = XOFF - bo_cur;
    if (ch < NCH - 1) {
      *(float4*)&xbuf[wa[0] + bo_next] = st0;
      *(float4*)&xbuf[wa[1] + bo_next] = st1;
      *(float4*)&xbuf[wa[2] + bo_next] = st2;
      *(float4*)&xbuf[wa[3] + bo_next] = st3;
      *(float4*)&xbuf[wa[4] + bo_next] = st4;
    }
    if (ch < NCH - 2) {
      st0 = *gp[0]; gp[0] += 40; st1 = *gp[1]; gp[1] += 40;
      st2 = *gp[2]; gp[2] += 40; st3 = *gp[3]; gp[3] += 40;
      st4 = *gp[4]; gp[4] += 40;
    }
    const int xb = bo_cur + grp * RSTR;
    rdg(xb +   0, A0, A1, A2, A3, A4);
    rdg(xb +  20, B0, B1, B2, B3, B4);
    step4(A0, A1, A2, A3, A4); rdg(xb +  40, A0, A1, A2, A3, A4);
    step4(B0, B1, B2, B3, B4); rdg(xb +  60, B0, B1, B2, B3, B4);
    step4(A0, A1, A2, A3, A4); rdg(xb +  80, A0, A1, A2, A3, A4);
    step4(B0, B1, B2, B3, B4); rdg(xb + 100, B0, B1, B2, B3, B4);
    step4(A0, A1, A2, A3, A4); rdg(xb + 120, A0, A1, A2, A3, A4);
    step4(B0, B1, B2, B3, B4); rdg(xb + 140, B0, B1, B2, B3, B4);
    step4(A0, A1, A2, A3, A4);
    step4(B0, B1, B2, B3, B4);
  }

  // ---- MLP head (single wave; no barriers needed) ----
  // residual input: hv_k already broadcast to all lanes; broadcast xlast too
  float xl0 = swz<SWZ_BCAST(0)>(xlast);
  float xl1 = swz<SWZ_BCAST(1)>(xlast);
  float xl2 = swz<SWZ_BCAST(2)>(xlast);
  float xl3 = swz<SWZ_BCAST(3)>(xlast);
  float xl4 = swz<SWZ_BCAST(4)>(xlast);
  float in5_0 = hv0 + xl0, in5_1 = hv1 + xl1, in5_2 = hv2 + xl2,
        in5_3 = hv3 + xl3, in5_4 = hv4 + xl4;

#pragma unroll
  for (int p = 0; p < 4; ++p) {
    int m = p * 8 + j;
    float acc = b1[m];
    acc = fmaf(W1[m * 5 + 0], in5_0, acc);
    acc = fmaf(W1[m * 5 + 1], in5_1, acc);
    acc = fmaf(W1[m * 5 + 2], in5_2, acc);
    acc = fmaf(W1[m * 5 + 3], in5_3, acc);
    acc = fmaf(W1[m * 5 + 4], in5_4, acc);
    s1[grp][m] = fmaxf(acc, 0.0f);
  }
  float y1[32];
#pragma unroll
  for (int k = 0; k < 32; ++k) y1[k] = s1[grp][k];

  auto dot32 = [&](const float* W, int m, const float* y, float b) {
    float acc = b;
    const float4* w4 = (const float4*)(W + m * 32);
#pragma unroll
    for (int k4 = 0; k4 < 8; ++k4) {
      float4 w = w4[k4];
      acc = fmaf(w.x, y[k4 * 4 + 0], acc);
      acc = fmaf(w.y, y[k4 * 4 + 1], acc);
      acc = fmaf(w.z, y[k4 * 4 + 2], acc);
      acc = fmaf(w.w, y[k4 * 4 + 3], acc);
    }
    return acc;
  };

#pragma unroll
  for (int p = 0; p < 4; ++p) {
    int m = p * 8 + j;
    s2[grp][m] = fmaxf(dot32(W2, m, y1, b2[m]), 0.0f);
  }
  float y2[32];
#pragma unroll
  for (int k = 0; k < 32; ++k) y2[k] = s2[grp][k];

  if (act) out[row * HD + j] = dot32(W3, j, y2, b3[j]);
}

extern "C" void kernel_launch(void* const* d_in, const int* in_sizes, int n_in,
                              void* d_out, int out_size, void* d_ws, size_t ws_size,
                              hipStream_t stream) {
  const float* x   = (const float*)d_in[0];
  const float* Wih = (const float*)d_in[1];
  const float* Whh = (const float*)d_in[2];
  const float* bih = (const float*)d_in[3];
  const float* bhh = (const float*)d_in[4];
  const float* W1  = (const float*)d_in[5];
  const float* b1  = (const float*)d_in[6];
  const float* W2  = (const float*)d_in[7];
  const float* b2  = (const float*)d_in[8];
  const float* W3  = (const float*)d_in[9];
  const float* b3  = (const float*)d_in[10];

  int B = in_sizes[0] / (TT * HD);
  int grid = (B + RPB - 1) / RPB;
  hipLaunchKernelGGL(lstm_mlp_kernel, dim3(grid), dim3(64), 0, stream,
                     x, Wih, Whh, bih, bhh, W1, b1, W2, b2, W3, b3,
                     (float*)d_out, B);
}